// Round 2
// baseline (577.664 us; speedup 1.0000x reference)
//
#include <hip/hip_runtime.h>
#include <hip/hip_bf16.h>
#include <stdint.h>

#define T_SEQ   2048
#define D_MODEL 1024
#define NHEAD   16
#define DHEAD   64
#define BATCH   4
#define MTOK    (BATCH * T_SEQ)   // 8192

typedef __attribute__((ext_vector_type(4))) float f32x4;
typedef __attribute__((ext_vector_type(8))) short bf16x8;

__device__ __forceinline__ f32x4 mfma16(bf16x8 a, bf16x8 b, f32x4 c) {
  return __builtin_amdgcn_mfma_f32_16x16x32_bf16(a, b, c, 0, 0, 0);
}

__device__ __forceinline__ short f2bf(float f) {
  __hip_bfloat16 h = __float2bfloat16(f);
  return *reinterpret_cast<short*>(&h);
}

#define GLD_LDS16(gp, lp)                                                      \
  __builtin_amdgcn_global_load_lds(                                            \
      (const __attribute__((address_space(1))) void*)(gp),                     \
      (__attribute__((address_space(3))) void*)(lp), 16, 0, 0)

// ---------------------------------------------------------------------------
// Weight transpose + fp32->bf16 convert: Wt[n][k] = W[k][n], 4 weights
// ---------------------------------------------------------------------------
__global__ __launch_bounds__(256) void transpose_w_kernel(
    const float* __restrict__ W0, const float* __restrict__ W1,
    const float* __restrict__ W2, const float* __restrict__ W3,
    short* __restrict__ out)
{
  const int z = blockIdx.z;
  const float* W = (z == 0) ? W0 : (z == 1) ? W1 : (z == 2) ? W2 : W3;
  short* o = out + (size_t)z * D_MODEL * D_MODEL;
  __shared__ float tile[32][33];
  const int n0 = blockIdx.x * 32, k0 = blockIdx.y * 32;
  const int c = threadIdx.x & 31, r = threadIdx.x >> 5;
#pragma unroll
  for (int i = 0; i < 4; i++)
    tile[r + i * 8][c] = W[(size_t)(k0 + r + i * 8) * D_MODEL + n0 + c];
  __syncthreads();
#pragma unroll
  for (int i = 0; i < 4; i++)
    o[(size_t)(n0 + r + i * 8) * D_MODEL + k0 + c] = f2bf(tile[c][r + i * 8]);
}

// ---------------------------------------------------------------------------
// x fp32 -> bf16 (8 elements / thread)
// ---------------------------------------------------------------------------
__global__ __launch_bounds__(256) void cvt_x_kernel(
    const float* __restrict__ x, short* __restrict__ xb)
{
  const size_t i = (size_t)blockIdx.x * 256 + threadIdx.x;
  const float4 a = ((const float4*)x)[i * 2];
  const float4 b = ((const float4*)x)[i * 2 + 1];
  bf16x8 o;
  o[0] = f2bf(a.x); o[1] = f2bf(a.y); o[2] = f2bf(a.z); o[3] = f2bf(a.w);
  o[4] = f2bf(b.x); o[5] = f2bf(b.y); o[6] = f2bf(b.z); o[7] = f2bf(b.w);
  ((bf16x8*)xb)[i] = o;
}

// ---------------------------------------------------------------------------
// GEMM: C[M][1024] = A[M][1024](bf16) * Bt[1024][1024]^T(bf16, N-major) + bias
// 128x128 tile, BK=32, 4 waves (2x2), each wave 64x64 via 4x4 16x16x32 MFMA.
// MODE 0: bf16 out (scale applied after bias). MODE 1: fp32 out.
// ---------------------------------------------------------------------------
template <int MODE>
__global__ __launch_bounds__(256) void gemm_bt(
    const short* __restrict__ A, const short* __restrict__ Bt,
    const float* __restrict__ bias, void* __restrict__ Cp, float scale)
{
  __shared__ __align__(16) short As[128 * 32];
  __shared__ __align__(16) short Bs[128 * 32];
  const int tid = threadIdx.x, lane = tid & 63, wid = tid >> 6;
  const int wr = wid >> 1, wc = wid & 1;
  const int lg = lane >> 4, ln = lane & 15;
  const int m0 = blockIdx.x * 128, n0 = blockIdx.y * 128;
  const int lrow = lane >> 2, lchunk = lane & 3;

  f32x4 acc[4][4];
#pragma unroll
  for (int i = 0; i < 4; i++)
#pragma unroll
    for (int j = 0; j < 4; j++) acc[i][j] = {0.f, 0.f, 0.f, 0.f};

  for (int k0 = 0; k0 < 1024; k0 += 32) {
#pragma unroll
    for (int s = 0; s < 2; ++s) {
      const int rbase = (wid * 2 + s) * 16;
      const short* gpa = A + (size_t)(m0 + rbase + lrow) * 1024 + k0 + lchunk * 8;
      GLD_LDS16(gpa, As + rbase * 32);
      const short* gpb = Bt + (size_t)(n0 + rbase + lrow) * 1024 + k0 + lchunk * 8;
      GLD_LDS16(gpb, Bs + rbase * 32);
    }
    __syncthreads();
    bf16x8 a[4], b[4];
#pragma unroll
    for (int mi = 0; mi < 4; mi++)
      a[mi] = *(const bf16x8*)(As + (wr * 64 + mi * 16 + ln) * 32 + lg * 8);
#pragma unroll
    for (int ni = 0; ni < 4; ni++)
      b[ni] = *(const bf16x8*)(Bs + (wc * 64 + ni * 16 + ln) * 32 + lg * 8);
#pragma unroll
    for (int mi = 0; mi < 4; mi++)
#pragma unroll
      for (int ni = 0; ni < 4; ni++)
        acc[mi][ni] = mfma16(a[mi], b[ni], acc[mi][ni]);
    __syncthreads();
  }

#pragma unroll
  for (int mi = 0; mi < 4; mi++)
#pragma unroll
    for (int ni = 0; ni < 4; ni++)
#pragma unroll
      for (int r = 0; r < 4; r++) {
        const int row = m0 + wr * 64 + mi * 16 + lg * 4 + r;
        const int col = n0 + wc * 64 + ni * 16 + ln;
        const float v = (acc[mi][ni][r] + bias[col]) * scale;
        if (MODE == 0)
          ((short*)Cp)[(size_t)row * 1024 + col] = f2bf(v);
        else
          ((float*)Cp)[(size_t)row * 1024 + col] = v;
      }
}

// ---------------------------------------------------------------------------
// V [8192][1024] token-major -> Vt[b][h][dh][t]  (64x64 tiles via LDS)
// ---------------------------------------------------------------------------
__global__ __launch_bounds__(256) void transpose_v_kernel(
    const short* __restrict__ V, short* __restrict__ Vt)
{
  const int bh = blockIdx.y, t0 = blockIdx.x * 64;
  const int b = bh >> 4, h = bh & 15;
  __shared__ __align__(16) short tile[64][72];
  const int tl = threadIdx.x >> 3, c = threadIdx.x & 7;
#pragma unroll
  for (int half = 0; half < 2; half++) {
    const int t = tl + half * 32;
    bf16x8 v = *(const bf16x8*)(V + (size_t)(b * T_SEQ + t0 + t) * 1024 + h * 64 + c * 8);
    *(bf16x8*)&tile[t][c * 8] = v;
  }
  __syncthreads();
#pragma unroll
  for (int half = 0; half < 2; half++) {
    const int dh = tl + half * 32;
    bf16x8 v;
#pragma unroll
    for (int j = 0; j < 8; j++) v[j] = tile[c * 8 + j][dh];
    *(bf16x8*)(Vt + ((size_t)bh * 64 + dh) * T_SEQ + t0 + c * 8) = v;
  }
}

// ---------------------------------------------------------------------------
// Causal flash attention. Q pre-scaled by 0.125*log2e (exp2 softmax domain).
// Block: 64 q-rows, 4 waves x 16 rows. KV tile = 64. Q,K token-major;
// Vt [bh][dh][t]. Output ctx token-major bf16.
// ---------------------------------------------------------------------------
__global__ __launch_bounds__(256) void attn_fwd(
    const short* __restrict__ Q, const short* __restrict__ K,
    const short* __restrict__ Vt, short* __restrict__ ctx)
{
  const int tid = threadIdx.x, lane = tid & 63, wid = tid >> 6;
  const int bh = blockIdx.y, b = bh >> 4, h = bh & 15;
  const int q0 = blockIdx.x * 64;
  const int qw = q0 + wid * 16;
  const int lg = lane >> 4, ln = lane & 15;

  __shared__ __align__(16) short Plds[4][16][72];

  bf16x8 qf[2];
  {
    const short* qp = Q + (size_t)(b * T_SEQ + qw + ln) * 1024 + h * 64 + lg * 8;
    qf[0] = *(const bf16x8*)qp;
    qf[1] = *(const bf16x8*)(qp + 32);
  }

  f32x4 o[4];
  float m_run[4], l_run[4];
#pragma unroll
  for (int i = 0; i < 4; i++) {
    o[i] = {0.f, 0.f, 0.f, 0.f};
    m_run[i] = -3.0e38f;
    l_run[i] = 0.f;
  }

  const int nt = blockIdx.x + 1;
  for (int it = 0; it < nt; ++it) {
    const int kv0 = it * 64;
    // S = Q K^T  (16 q-rows x 64 kv-cols per wave)
    f32x4 s[4];
#pragma unroll
    for (int ni = 0; ni < 4; ni++) {
      const short* kp = K + (size_t)(b * T_SEQ + kv0 + ni * 16 + ln) * 1024 + h * 64 + lg * 8;
      bf16x8 k0v = *(const bf16x8*)kp;
      bf16x8 k1v = *(const bf16x8*)(kp + 32);
      f32x4 z = {0.f, 0.f, 0.f, 0.f};
      z = mfma16(qf[0], k0v, z);
      z = mfma16(qf[1], k1v, z);
      s[ni] = z;
    }
    // causal mask (rows qw+lg*4+r, cols kv0+ni*16+ln)
    if (kv0 + 63 > qw) {
#pragma unroll
      for (int ni = 0; ni < 4; ni++) {
        const int col = kv0 + ni * 16 + ln;
#pragma unroll
        for (int r = 0; r < 4; r++) {
          const int row = qw + lg * 4 + r;
          if (col > row) s[ni][r] = -3.0e38f;
        }
      }
    }
    // row max across the 16-lane group
    float tmax[4];
#pragma unroll
    for (int r = 0; r < 4; r++)
      tmax[r] = fmaxf(fmaxf(s[0][r], s[1][r]), fmaxf(s[2][r], s[3][r]));
#pragma unroll
    for (int off = 1; off < 16; off <<= 1)
#pragma unroll
      for (int r = 0; r < 4; r++)
        tmax[r] = fmaxf(tmax[r], __shfl_xor(tmax[r], off));
    // online rescale
    float tsum[4];
#pragma unroll
    for (int r = 0; r < 4; r++) {
      const float mn = fmaxf(m_run[r], tmax[r]);
      const float sc = exp2f(m_run[r] - mn);
      m_run[r] = mn;
      l_run[r] *= sc;
#pragma unroll
      for (int ni = 0; ni < 4; ni++) o[ni][r] *= sc;
      tsum[r] = 0.f;
    }
    // P = exp2(S - m) -> bf16 -> per-wave LDS tile [16][64 (+8 pad)]
#pragma unroll
    for (int ni = 0; ni < 4; ni++)
#pragma unroll
      for (int r = 0; r < 4; r++) {
        const float p = exp2f(s[ni][r] - m_run[r]);
        tsum[r] += p;
        Plds[wid][lg * 4 + r][ni * 16 + ln] = f2bf(p);
      }
#pragma unroll
    for (int off = 1; off < 16; off <<= 1)
#pragma unroll
      for (int r = 0; r < 4; r++) tsum[r] += __shfl_xor(tsum[r], off);
#pragma unroll
    for (int r = 0; r < 4; r++) l_run[r] += tsum[r];
    // O += P * V  (A from Plds, B from Vt: contiguous along t)
    bf16x8 pf0 = *(const bf16x8*)&Plds[wid][ln][lg * 8];
    bf16x8 pf1 = *(const bf16x8*)&Plds[wid][ln][32 + lg * 8];
#pragma unroll
    for (int ni = 0; ni < 4; ni++) {
      const short* vp = Vt + ((size_t)bh * 64 + ni * 16 + ln) * T_SEQ + kv0 + lg * 8;
      bf16x8 v0 = *(const bf16x8*)vp;
      bf16x8 v1 = *(const bf16x8*)(vp + 32);
      o[ni] = mfma16(pf0, v0, o[ni]);
      o[ni] = mfma16(pf1, v1, o[ni]);
    }
  }
  // epilogue: ctx = O / l
#pragma unroll
  for (int ni = 0; ni < 4; ni++) {
#pragma unroll
    for (int r = 0; r < 4; r++) {
      const float inv = 1.0f / l_run[r];
      const float v = o[ni][r] * inv;
      ctx[(size_t)(b * T_SEQ + qw + lg * 4 + r) * 1024 + h * 64 + ni * 16 + ln] = f2bf(v);
    }
  }
}

// ---------------------------------------------------------------------------
extern "C" void kernel_launch(void* const* d_in, const int* in_sizes, int n_in,
                              void* d_out, int out_size, void* d_ws, size_t ws_size,
                              hipStream_t stream)
{
  (void)in_sizes; (void)n_in; (void)out_size; (void)ws_size;
  const float* x  = (const float*)d_in[0];
  // d_in[1] = causal mask (triu, k=1) — structure is known, not read
  const float* WQ = (const float*)d_in[2];
  const float* bQ = (const float*)d_in[3];
  const float* WK = (const float*)d_in[4];
  const float* bK = (const float*)d_in[5];
  const float* WV = (const float*)d_in[6];
  const float* bV = (const float*)d_in[7];
  const float* WO = (const float*)d_in[8];
  const float* bO = (const float*)d_in[9];
  float* out = (float*)d_out;

  const size_t MB = 1024ull * 1024ull;
  char* w = (char*)d_ws;
  short* xb = (short*)(w);             // 16MB; reused as ctx after QKV GEMMs
  short* Wt = (short*)(w + 16 * MB);   // 8MB: WQt,WKt,WVt,WOt bf16
  short* Qb = (short*)(w + 24 * MB);   // 16MB
  short* Kb = (short*)(w + 40 * MB);   // 16MB
  short* Vb = (short*)(w + 56 * MB);   // 16MB
  short* Vt = (short*)(w + 72 * MB);   // 16MB
  short* ctx = xb;

  transpose_w_kernel<<<dim3(32, 32, 4), 256, 0, stream>>>(WQ, WK, WV, WO, Wt);
  cvt_x_kernel<<<dim3(MTOK * D_MODEL / 8 / 256), 256, 0, stream>>>(x, xb);

  const float qscale = 0.125f * 1.4426950408889634f;  // fold 1/sqrt(64) * log2(e)
  gemm_bt<0><<<dim3(64, 8), 256, 0, stream>>>(xb, Wt + 0 * D_MODEL * D_MODEL, bQ, Qb, qscale);
  gemm_bt<0><<<dim3(64, 8), 256, 0, stream>>>(xb, Wt + 1 * D_MODEL * D_MODEL, bK, Kb, 1.0f);
  gemm_bt<0><<<dim3(64, 8), 256, 0, stream>>>(xb, Wt + 2 * D_MODEL * D_MODEL, bV, Vb, 1.0f);

  transpose_v_kernel<<<dim3(32, 64), 256, 0, stream>>>(Vb, Vt);
  attn_fwd<<<dim3(32, 64), 256, 0, stream>>>(Qb, Kb, Vt, ctx);

  gemm_bt<1><<<dim3(64, 8), 256, 0, stream>>>(ctx, Wt + 3 * D_MODEL * D_MODEL, bO, out, 1.0f);
}

// Round 3
// 445.172 us; speedup vs baseline: 1.2976x; 1.2976x over previous
//
#include <hip/hip_runtime.h>
#include <hip/hip_bf16.h>
#include <stdint.h>

#define T_SEQ   2048
#define D_MODEL 1024
#define NHEAD   16
#define DHEAD   64
#define BATCH   4
#define MTOK    (BATCH * T_SEQ)   // 8192

typedef __attribute__((ext_vector_type(4))) float f32x4;
typedef __attribute__((ext_vector_type(8))) short bf16x8;

__device__ __forceinline__ f32x4 mfma16(bf16x8 a, bf16x8 b, f32x4 c) {
  return __builtin_amdgcn_mfma_f32_16x16x32_bf16(a, b, c, 0, 0, 0);
}

__device__ __forceinline__ short f2bf(float f) {
  __hip_bfloat16 h = __float2bfloat16(f);
  return *reinterpret_cast<short*>(&h);
}

#define GLD_LDS16(gp, lp)                                                      \
  __builtin_amdgcn_global_load_lds(                                            \
      (const __attribute__((address_space(1))) void*)(gp),                     \
      (__attribute__((address_space(3))) void*)(lp), 16, 0, 0)

// ---------------------------------------------------------------------------
// Weight transpose + fp32->bf16 convert: Wt[n][k] = W[k][n], 4 weights
// ---------------------------------------------------------------------------
__global__ __launch_bounds__(256) void transpose_w_kernel(
    const float* __restrict__ W0, const float* __restrict__ W1,
    const float* __restrict__ W2, const float* __restrict__ W3,
    short* __restrict__ out)
{
  const int z = blockIdx.z;
  const float* W = (z == 0) ? W0 : (z == 1) ? W1 : (z == 2) ? W2 : W3;
  short* o = out + (size_t)z * D_MODEL * D_MODEL;
  __shared__ float tile[32][33];
  const int n0 = blockIdx.x * 32, k0 = blockIdx.y * 32;
  const int c = threadIdx.x & 31, r = threadIdx.x >> 5;
#pragma unroll
  for (int i = 0; i < 4; i++)
    tile[r + i * 8][c] = W[(size_t)(k0 + r + i * 8) * D_MODEL + n0 + c];
  __syncthreads();
#pragma unroll
  for (int i = 0; i < 4; i++)
    o[(size_t)(n0 + r + i * 8) * D_MODEL + k0 + c] = f2bf(tile[c][r + i * 8]);
}

// ---------------------------------------------------------------------------
// x fp32 -> bf16 (8 elements / thread)
// ---------------------------------------------------------------------------
__global__ __launch_bounds__(256) void cvt_x_kernel(
    const float* __restrict__ x, short* __restrict__ xb)
{
  const size_t i = (size_t)blockIdx.x * 256 + threadIdx.x;
  const float4 a = ((const float4*)x)[i * 2];
  const float4 b = ((const float4*)x)[i * 2 + 1];
  bf16x8 o;
  o[0] = f2bf(a.x); o[1] = f2bf(a.y); o[2] = f2bf(a.z); o[3] = f2bf(a.w);
  o[4] = f2bf(b.x); o[5] = f2bf(b.y); o[6] = f2bf(b.z); o[7] = f2bf(b.w);
  ((bf16x8*)xb)[i] = o;
}

// ---------------------------------------------------------------------------
// GEMM: C[M][1024] = A[M][1024](bf16) * Bt[1024][1024]^T(bf16, N-major) + bias
// 128x128 tile, BK=32, 4 waves (2x2), each wave 64x64 via 4x4 16x16x32 MFMA.
// MODE 0: bf16 out (scale applied after bias). MODE 1: fp32 out.
// ---------------------------------------------------------------------------
template <int MODE>
__global__ __launch_bounds__(256) void gemm_bt(
    const short* __restrict__ A, const short* __restrict__ Bt,
    const float* __restrict__ bias, void* __restrict__ Cp, float scale)
{
  __shared__ __align__(16) short As[128 * 32];
  __shared__ __align__(16) short Bs[128 * 32];
  const int tid = threadIdx.x, lane = tid & 63, wid = tid >> 6;
  const int wr = wid >> 1, wc = wid & 1;
  const int lg = lane >> 4, ln = lane & 15;
  const int m0 = blockIdx.x * 128, n0 = blockIdx.y * 128;
  const int lrow = lane >> 2, lchunk = lane & 3;

  f32x4 acc[4][4];
#pragma unroll
  for (int i = 0; i < 4; i++)
#pragma unroll
    for (int j = 0; j < 4; j++) acc[i][j] = {0.f, 0.f, 0.f, 0.f};

  for (int k0 = 0; k0 < 1024; k0 += 32) {
#pragma unroll
    for (int s = 0; s < 2; ++s) {
      const int rbase = (wid * 2 + s) * 16;
      const short* gpa = A + (size_t)(m0 + rbase + lrow) * 1024 + k0 + lchunk * 8;
      GLD_LDS16(gpa, As + rbase * 32);
      const short* gpb = Bt + (size_t)(n0 + rbase + lrow) * 1024 + k0 + lchunk * 8;
      GLD_LDS16(gpb, Bs + rbase * 32);
    }
    __syncthreads();
    bf16x8 a[4], b[4];
#pragma unroll
    for (int mi = 0; mi < 4; mi++)
      a[mi] = *(const bf16x8*)(As + (wr * 64 + mi * 16 + ln) * 32 + lg * 8);
#pragma unroll
    for (int ni = 0; ni < 4; ni++)
      b[ni] = *(const bf16x8*)(Bs + (wc * 64 + ni * 16 + ln) * 32 + lg * 8);
#pragma unroll
    for (int mi = 0; mi < 4; mi++)
#pragma unroll
      for (int ni = 0; ni < 4; ni++)
        acc[mi][ni] = mfma16(a[mi], b[ni], acc[mi][ni]);
    __syncthreads();
  }

#pragma unroll
  for (int mi = 0; mi < 4; mi++)
#pragma unroll
    for (int ni = 0; ni < 4; ni++)
#pragma unroll
      for (int r = 0; r < 4; r++) {
        const int row = m0 + wr * 64 + mi * 16 + lg * 4 + r;
        const int col = n0 + wc * 64 + ni * 16 + ln;
        const float v = (acc[mi][ni][r] + bias[col]) * scale;
        if (MODE == 0)
          ((short*)Cp)[(size_t)row * 1024 + col] = f2bf(v);
        else
          ((float*)Cp)[(size_t)row * 1024 + col] = v;
      }
}

// ---------------------------------------------------------------------------
// V [8192][1024] token-major -> Vt[b][h][dh][t]  (64x64 tiles via LDS)
// ---------------------------------------------------------------------------
__global__ __launch_bounds__(256) void transpose_v_kernel(
    const short* __restrict__ V, short* __restrict__ Vt)
{
  const int bh = blockIdx.y, t0 = blockIdx.x * 64;
  const int b = bh >> 4, h = bh & 15;
  __shared__ __align__(16) short tile[64][72];
  const int tl = threadIdx.x >> 3, c = threadIdx.x & 7;
#pragma unroll
  for (int half = 0; half < 2; half++) {
    const int t = tl + half * 32;
    bf16x8 v = *(const bf16x8*)(V + (size_t)(b * T_SEQ + t0 + t) * 1024 + h * 64 + c * 8);
    *(bf16x8*)&tile[t][c * 8] = v;
  }
  __syncthreads();
#pragma unroll
  for (int half = 0; half < 2; half++) {
    const int dh = tl + half * 32;
    bf16x8 v;
#pragma unroll
    for (int j = 0; j < 8; j++) v[j] = tile[c * 8 + j][dh];
    *(bf16x8*)(Vt + ((size_t)bh * 64 + dh) * T_SEQ + t0 + c * 8) = v;
  }
}

// ---------------------------------------------------------------------------
// Causal flash attention, v2.
// Changes vs v1: (a) causal load-balance — block x processes q-tiles x and
// 31-x (each block = exactly 17 KV-128-tiles of work); (b) KVBLK 64->128 —
// amortizes the per-tile shfl reduce chains over 2x columns and doubles
// batched loads in flight. 4 waves x 16 q-rows; Q pre-scaled 0.125*log2e.
// ---------------------------------------------------------------------------
__global__ __launch_bounds__(256) void attn_fwd(
    const short* __restrict__ Q, const short* __restrict__ K,
    const short* __restrict__ Vt, short* __restrict__ ctx)
{
  const int tid = threadIdx.x, lane = tid & 63, wid = tid >> 6;
  const int bh = blockIdx.y, b = bh >> 4, h = bh & 15;
  const int lg = lane >> 4, ln = lane & 15;

  __shared__ __align__(16) short Plds[4][16][136];

#pragma unroll 1
  for (int pass = 0; pass < 2; ++pass) {
    const int qt = (pass == 0) ? (int)blockIdx.x : 31 - (int)blockIdx.x;
    const int q0 = qt * 64;
    const int qw = q0 + wid * 16;

    bf16x8 qf[2];
    {
      const short* qp = Q + (size_t)(b * T_SEQ + qw + ln) * 1024 + h * 64 + lg * 8;
      qf[0] = *(const bf16x8*)qp;
      qf[1] = *(const bf16x8*)(qp + 32);
    }

    f32x4 o[4];
    float m_run[4], l_run[4];
#pragma unroll
    for (int i = 0; i < 4; i++) {
      o[i] = {0.f, 0.f, 0.f, 0.f};
      m_run[i] = -3.0e38f;
      l_run[i] = 0.f;
    }

    const int nt = (q0 + 64 + 127) >> 7;   // KV tiles of 128
    for (int it = 0; it < nt; ++it) {
      const int kv0 = it * 128;
      // S = Q K^T  (16 q-rows x 128 kv-cols per wave)
      f32x4 s[8];
#pragma unroll
      for (int ni = 0; ni < 8; ni++) {
        const short* kp = K + (size_t)(b * T_SEQ + kv0 + ni * 16 + ln) * 1024 + h * 64 + lg * 8;
        bf16x8 k0v = *(const bf16x8*)kp;
        bf16x8 k1v = *(const bf16x8*)(kp + 32);
        f32x4 z = {0.f, 0.f, 0.f, 0.f};
        z = mfma16(qf[0], k0v, z);
        z = mfma16(qf[1], k1v, z);
        s[ni] = z;
      }
      // causal mask (rows qw+lg*4+r, cols kv0+ni*16+ln)
      if (kv0 + 127 > qw) {
#pragma unroll
        for (int ni = 0; ni < 8; ni++) {
          const int col = kv0 + ni * 16 + ln;
#pragma unroll
          for (int r = 0; r < 4; r++) {
            const int row = qw + lg * 4 + r;
            if (col > row) s[ni][r] = -3.0e38f;
          }
        }
      }
      // row max across the 16-lane group
      float tmax[4];
#pragma unroll
      for (int r = 0; r < 4; r++) {
        float a0 = fmaxf(fmaxf(s[0][r], s[1][r]), fmaxf(s[2][r], s[3][r]));
        float a1 = fmaxf(fmaxf(s[4][r], s[5][r]), fmaxf(s[6][r], s[7][r]));
        tmax[r] = fmaxf(a0, a1);
      }
#pragma unroll
      for (int off = 1; off < 16; off <<= 1)
#pragma unroll
        for (int r = 0; r < 4; r++)
          tmax[r] = fmaxf(tmax[r], __shfl_xor(tmax[r], off));
      // online rescale
      float tsum[4];
#pragma unroll
      for (int r = 0; r < 4; r++) {
        const float mn = fmaxf(m_run[r], tmax[r]);
        const float sc = exp2f(m_run[r] - mn);
        m_run[r] = mn;
        l_run[r] *= sc;
#pragma unroll
        for (int ni = 0; ni < 4; ni++) o[ni][r] *= sc;
        tsum[r] = 0.f;
      }
      // P = exp2(S - m) -> bf16 -> per-wave LDS tile [16][128 (+8 pad)]
#pragma unroll
      for (int ni = 0; ni < 8; ni++)
#pragma unroll
        for (int r = 0; r < 4; r++) {
          const float p = exp2f(s[ni][r] - m_run[r]);
          tsum[r] += p;
          Plds[wid][lg * 4 + r][ni * 16 + ln] = f2bf(p);
        }
#pragma unroll
      for (int off = 1; off < 16; off <<= 1)
#pragma unroll
        for (int r = 0; r < 4; r++) tsum[r] += __shfl_xor(tsum[r], off);
#pragma unroll
      for (int r = 0; r < 4; r++) l_run[r] += tsum[r];
      // O += P * V  (A from Plds row=ln, B from Vt contiguous along t)
#pragma unroll
      for (int c = 0; c < 4; c++) {
        const bf16x8 pf = *(const bf16x8*)&Plds[wid][ln][c * 32 + lg * 8];
#pragma unroll
        for (int ni = 0; ni < 4; ni++) {
          const short* vp = Vt + ((size_t)bh * 64 + ni * 16 + ln) * T_SEQ + kv0 + c * 32 + lg * 8;
          o[ni] = mfma16(pf, *(const bf16x8*)vp, o[ni]);
        }
      }
    }
    // epilogue: ctx = O / l
#pragma unroll
    for (int ni = 0; ni < 4; ni++) {
#pragma unroll
      for (int r = 0; r < 4; r++) {
        const float inv = 1.0f / l_run[r];
        const float v = o[ni][r] * inv;
        ctx[(size_t)(b * T_SEQ + qw + lg * 4 + r) * 1024 + h * 64 + ni * 16 + ln] = f2bf(v);
      }
    }
  }
}

// ---------------------------------------------------------------------------
extern "C" void kernel_launch(void* const* d_in, const int* in_sizes, int n_in,
                              void* d_out, int out_size, void* d_ws, size_t ws_size,
                              hipStream_t stream)
{
  (void)in_sizes; (void)n_in; (void)out_size; (void)ws_size;
  const float* x  = (const float*)d_in[0];
  // d_in[1] = causal mask (triu, k=1) — structure is known, not read
  const float* WQ = (const float*)d_in[2];
  const float* bQ = (const float*)d_in[3];
  const float* WK = (const float*)d_in[4];
  const float* bK = (const float*)d_in[5];
  const float* WV = (const float*)d_in[6];
  const float* bV = (const float*)d_in[7];
  const float* WO = (const float*)d_in[8];
  const float* bO = (const float*)d_in[9];
  float* out = (float*)d_out;

  const size_t MB = 1024ull * 1024ull;
  char* w = (char*)d_ws;
  short* xb = (short*)(w);             // 16MB; reused as ctx after QKV GEMMs
  short* Wt = (short*)(w + 16 * MB);   // 8MB: WQt,WKt,WVt,WOt bf16
  short* Qb = (short*)(w + 24 * MB);   // 16MB
  short* Kb = (short*)(w + 40 * MB);   // 16MB
  short* Vb = (short*)(w + 56 * MB);   // 16MB
  short* Vt = (short*)(w + 72 * MB);   // 16MB
  short* ctx = xb;

  transpose_w_kernel<<<dim3(32, 32, 4), 256, 0, stream>>>(WQ, WK, WV, WO, Wt);
  cvt_x_kernel<<<dim3(MTOK * D_MODEL / 8 / 256), 256, 0, stream>>>(x, xb);

  const float qscale = 0.125f * 1.4426950408889634f;  // fold 1/sqrt(64) * log2(e)
  gemm_bt<0><<<dim3(64, 8), 256, 0, stream>>>(xb, Wt + 0 * D_MODEL * D_MODEL, bQ, Qb, qscale);
  gemm_bt<0><<<dim3(64, 8), 256, 0, stream>>>(xb, Wt + 1 * D_MODEL * D_MODEL, bK, Kb, 1.0f);
  gemm_bt<0><<<dim3(64, 8), 256, 0, stream>>>(xb, Wt + 2 * D_MODEL * D_MODEL, bV, Vb, 1.0f);

  transpose_v_kernel<<<dim3(32, 64), 256, 0, stream>>>(Vb, Vt);
  attn_fwd<<<dim3(16, 64), 256, 0, stream>>>(Qb, Kb, Vt, ctx);

  gemm_bt<1><<<dim3(64, 8), 256, 0, stream>>>(ctx, Wt + 3 * D_MODEL * D_MODEL, bO, out, 1.0f);
}

// Round 4
// 333.556 us; speedup vs baseline: 1.7318x; 1.3346x over previous
//
#include <hip/hip_runtime.h>
#include <hip/hip_bf16.h>
#include <stdint.h>

#define T_SEQ   2048
#define D_MODEL 1024
#define NHEAD   16
#define DHEAD   64
#define BATCH   4
#define MTOK    (BATCH * T_SEQ)   // 8192

typedef __attribute__((ext_vector_type(4))) float f32x4;
typedef __attribute__((ext_vector_type(16))) float f32x16;
typedef __attribute__((ext_vector_type(8))) short bf16x8;
typedef __attribute__((ext_vector_type(4))) short s16x4;
typedef __attribute__((ext_vector_type(4))) unsigned u32x4;

__device__ __forceinline__ f32x4 mfma16(bf16x8 a, bf16x8 b, f32x4 c) {
  return __builtin_amdgcn_mfma_f32_16x16x32_bf16(a, b, c, 0, 0, 0);
}
__device__ __forceinline__ f32x16 mfma32(bf16x8 a, bf16x8 b, f32x16 c) {
  return __builtin_amdgcn_mfma_f32_32x32x16_bf16(a, b, c, 0, 0, 0);
}

__device__ __forceinline__ short f2bf(float f) {
  __hip_bfloat16 h = __float2bfloat16(f);
  return *reinterpret_cast<short*>(&h);
}

// v_cvt_pk_bf16_f32: dst = {lo16: bf16(a), hi16: bf16(b)} (no builtin on gfx950)
__device__ __forceinline__ unsigned cvtpk(float a, float b) {
  unsigned r;
  asm("v_cvt_pk_bf16_f32 %0, %1, %2" : "=v"(r) : "v"(a), "v"(b));
  return r;
}

union PB { u32x4 u; bf16x8 b; };

#define GLD_LDS16(gp, lp)                                                      \
  __builtin_amdgcn_global_load_lds(                                            \
      (const __attribute__((address_space(1))) void*)(gp),                     \
      (__attribute__((address_space(3))) void*)(lp), 16, 0, 0)

// ---------------------------------------------------------------------------
// Weight transpose + fp32->bf16 convert: Wt[n][k] = W[k][n], 4 weights
// ---------------------------------------------------------------------------
__global__ __launch_bounds__(256) void transpose_w_kernel(
    const float* __restrict__ W0, const float* __restrict__ W1,
    const float* __restrict__ W2, const float* __restrict__ W3,
    short* __restrict__ out)
{
  const int z = blockIdx.z;
  const float* W = (z == 0) ? W0 : (z == 1) ? W1 : (z == 2) ? W2 : W3;
  short* o = out + (size_t)z * D_MODEL * D_MODEL;
  __shared__ float tile[32][33];
  const int n0 = blockIdx.x * 32, k0 = blockIdx.y * 32;
  const int c = threadIdx.x & 31, r = threadIdx.x >> 5;
#pragma unroll
  for (int i = 0; i < 4; i++)
    tile[r + i * 8][c] = W[(size_t)(k0 + r + i * 8) * D_MODEL + n0 + c];
  __syncthreads();
#pragma unroll
  for (int i = 0; i < 4; i++)
    o[(size_t)(n0 + r + i * 8) * D_MODEL + k0 + c] = f2bf(tile[c][r + i * 8]);
}

// ---------------------------------------------------------------------------
// x fp32 -> bf16 (8 elements / thread)
// ---------------------------------------------------------------------------
__global__ __launch_bounds__(256) void cvt_x_kernel(
    const float* __restrict__ x, short* __restrict__ xb)
{
  const size_t i = (size_t)blockIdx.x * 256 + threadIdx.x;
  const float4 a = ((const float4*)x)[i * 2];
  const float4 b = ((const float4*)x)[i * 2 + 1];
  bf16x8 o;
  o[0] = f2bf(a.x); o[1] = f2bf(a.y); o[2] = f2bf(a.z); o[3] = f2bf(a.w);
  o[4] = f2bf(b.x); o[5] = f2bf(b.y); o[6] = f2bf(b.z); o[7] = f2bf(b.w);
  ((bf16x8*)xb)[i] = o;
}

// ---------------------------------------------------------------------------
// GEMM: C[M][1024] = A[M][1024](bf16) * Bt[1024][1024]^T(bf16, N-major) + bias
// 128x128 tile, BK=32, 4 waves (2x2), each wave 64x64 via 4x4 16x16x32 MFMA.
// MODE 0: bf16 out (scale applied after bias). MODE 1: fp32 out.
// ---------------------------------------------------------------------------
template <int MODE>
__global__ __launch_bounds__(256) void gemm_bt(
    const short* __restrict__ A, const short* __restrict__ Bt,
    const float* __restrict__ bias, void* __restrict__ Cp, float scale)
{
  __shared__ __align__(16) short As[128 * 32];
  __shared__ __align__(16) short Bs[128 * 32];
  const int tid = threadIdx.x, lane = tid & 63, wid = tid >> 6;
  const int wr = wid >> 1, wc = wid & 1;
  const int lg = lane >> 4, ln = lane & 15;
  const int m0 = blockIdx.x * 128, n0 = blockIdx.y * 128;
  const int lrow = lane >> 2, lchunk = lane & 3;

  f32x4 acc[4][4];
#pragma unroll
  for (int i = 0; i < 4; i++)
#pragma unroll
    for (int j = 0; j < 4; j++) acc[i][j] = {0.f, 0.f, 0.f, 0.f};

  for (int k0 = 0; k0 < 1024; k0 += 32) {
#pragma unroll
    for (int s = 0; s < 2; ++s) {
      const int rbase = (wid * 2 + s) * 16;
      const short* gpa = A + (size_t)(m0 + rbase + lrow) * 1024 + k0 + lchunk * 8;
      GLD_LDS16(gpa, As + rbase * 32);
      const short* gpb = Bt + (size_t)(n0 + rbase + lrow) * 1024 + k0 + lchunk * 8;
      GLD_LDS16(gpb, Bs + rbase * 32);
    }
    __syncthreads();
    bf16x8 a[4], b[4];
#pragma unroll
    for (int mi = 0; mi < 4; mi++)
      a[mi] = *(const bf16x8*)(As + (wr * 64 + mi * 16 + ln) * 32 + lg * 8);
#pragma unroll
    for (int ni = 0; ni < 4; ni++)
      b[ni] = *(const bf16x8*)(Bs + (wc * 64 + ni * 16 + ln) * 32 + lg * 8);
#pragma unroll
    for (int mi = 0; mi < 4; mi++)
#pragma unroll
      for (int ni = 0; ni < 4; ni++)
        acc[mi][ni] = mfma16(a[mi], b[ni], acc[mi][ni]);
    __syncthreads();
  }

#pragma unroll
  for (int mi = 0; mi < 4; mi++)
#pragma unroll
    for (int ni = 0; ni < 4; ni++)
#pragma unroll
      for (int r = 0; r < 4; r++) {
        const int row = m0 + wr * 64 + mi * 16 + lg * 4 + r;
        const int col = n0 + wc * 64 + ni * 16 + ln;
        const float v = (acc[mi][ni][r] + bias[col]) * scale;
        if (MODE == 0)
          ((short*)Cp)[(size_t)row * 1024 + col] = f2bf(v);
        else
          ((float*)Cp)[(size_t)row * 1024 + col] = v;
      }
}

// ---------------------------------------------------------------------------
// V [8192][1024] token-major -> Vt[b][h][dh][t]  (64x64 tiles via LDS)
// ---------------------------------------------------------------------------
__global__ __launch_bounds__(256) void transpose_v_kernel(
    const short* __restrict__ V, short* __restrict__ Vt)
{
  const int bh = blockIdx.y, t0 = blockIdx.x * 64;
  const int b = bh >> 4, h = bh & 15;
  __shared__ __align__(16) short tile[64][72];
  const int tl = threadIdx.x >> 3, c = threadIdx.x & 7;
#pragma unroll
  for (int half = 0; half < 2; half++) {
    const int t = tl + half * 32;
    bf16x8 v = *(const bf16x8*)(V + (size_t)(b * T_SEQ + t0 + t) * 1024 + h * 64 + c * 8);
    *(bf16x8*)&tile[t][c * 8] = v;
  }
  __syncthreads();
#pragma unroll
  for (int half = 0; half < 2; half++) {
    const int dh = tl + half * 32;
    bf16x8 v;
#pragma unroll
    for (int j = 0; j < 8; j++) v[j] = tile[c * 8 + j][dh];
    *(bf16x8*)(Vt + ((size_t)bh * 64 + dh) * T_SEQ + t0 + c * 8) = v;
  }
}

// ---------------------------------------------------------------------------
// Causal flash attention v3: swapped QK^T, 32x32x16 MFMA, in-register softmax.
// One wave per block, 32 q-rows per wave. S^T = K·Q^T puts q = lane&31 ->
// softmax state (m,l) is a per-lane scalar; P redistributed to PV B-fragment
// via cvt_pk_bf16 + shfl_xor(32) + select (no LDS at all). PV computed as
// O^T = Vt·P so the online rescale stays lane-local. Q pre-scaled 0.125*log2e.
// Grid: x = q-tile (descending size order for backfill balance), y = b*16+h.
// ---------------------------------------------------------------------------
__global__ __launch_bounds__(64) void attn_fwd(
    const short* __restrict__ Q, const short* __restrict__ K,
    const short* __restrict__ Vt, short* __restrict__ ctx)
{
  const int lane = threadIdx.x;
  const int hi = lane >> 5, lq = lane & 31;
  const int qt = 63 - (int)blockIdx.x;          // longest blocks dispatch first
  const int bh = blockIdx.y, b = bh >> 4, h = bh & 15;
  const int qw = qt * 32;
  const int q = qw + lq;

  // Q B-fragments: Q[q=lane&31][dh = c*16 + hi*8 + j]
  bf16x8 qf[4];
  {
    const short* qp = Q + (size_t)(b * T_SEQ + q) * 1024 + h * 64 + hi * 8;
#pragma unroll
    for (int c = 0; c < 4; c++) qf[c] = *(const bf16x8*)(qp + c * 16);
  }

  f32x16 o0, o1;
#pragma unroll
  for (int i = 0; i < 16; i++) { o0[i] = 0.f; o1[i] = 0.f; }
  float m_run = -3.0e38f, l_run = 0.f;

  const int nt = (qw + 95) >> 6;                 // kv tiles of 64
  for (int it = 0; it < nt; ++it) {
    const int kv0 = it * 64;
    // ---- loads for this tile (issued before any use) ----
    bf16x8 kf[2][4], vf[2][4];
    const short* kp = K + (size_t)(b * T_SEQ + kv0 + lq) * 1024 + h * 64 + hi * 8;
#pragma unroll
    for (int kh = 0; kh < 2; kh++)
#pragma unroll
      for (int c = 0; c < 4; c++)
        kf[kh][c] = *(const bf16x8*)(kp + kh * 32 * 1024 + c * 16);
    const short* vp = Vt + (size_t)(bh * 64 + lq) * T_SEQ + kv0 + hi * 8;
#pragma unroll
    for (int dh = 0; dh < 2; dh++)
#pragma unroll
      for (int kc = 0; kc < 4; kc++)
        vf[dh][kc] = *(const bf16x8*)(vp + dh * 32 * T_SEQ + kc * 16);

    // ---- S^T[k][q] = K·Q^T : col=lane&31=q, row k=(reg&3)+8*(reg>>2)+4*hi ----
    f32x16 s0, s1;
#pragma unroll
    for (int i = 0; i < 16; i++) { s0[i] = 0.f; s1[i] = 0.f; }
#pragma unroll
    for (int c = 0; c < 4; c++) s0 = mfma32(kf[0][c], qf[c], s0);
#pragma unroll
    for (int c = 0; c < 4; c++) s1 = mfma32(kf[1][c], qf[c], s1);

    // ---- causal mask: k = kv0 + (h2*32) + cst + 4*hi  vs  q ----
    if (kv0 + 63 > qw) {
      const int qrel = q - kv0 - 4 * hi;
#pragma unroll
      for (int r = 0; r < 16; r++) {
        const int cst = (r & 3) + 8 * (r >> 2);
        if (cst > qrel) s0[r] = -3.0e38f;
        if (cst + 32 > qrel) s1[r] = -3.0e38f;
      }
    }

    // ---- in-lane row max + single cross-half exchange ----
    float mx;
    {
      float t[8];
#pragma unroll
      for (int i = 0; i < 8; i++)
        t[i] = fmaxf(fmaxf(s0[i], s0[i + 8]), fmaxf(s1[i], s1[i + 8]));
      const float a0 = fmaxf(fmaxf(t[0], t[1]), fmaxf(t[2], t[3]));
      const float a1 = fmaxf(fmaxf(t[4], t[5]), fmaxf(t[6], t[7]));
      mx = fmaxf(a0, a1);
      mx = fmaxf(mx, __shfl_xor(mx, 32));
    }
    const float mn = fmaxf(m_run, mx);
    const float rr = exp2f(m_run - mn);
    m_run = mn;

    // ---- P = exp2(S - m), row sum ----
#pragma unroll
    for (int i = 0; i < 16; i++) s0[i] = exp2f(s0[i] - mn);
#pragma unroll
    for (int i = 0; i < 16; i++) s1[i] = exp2f(s1[i] - mn);
    float ts;
    {
      float t[8];
#pragma unroll
      for (int i = 0; i < 8; i++) t[i] = (s0[i] + s0[i + 8]) + (s1[i] + s1[i + 8]);
      ts = ((t[0] + t[1]) + (t[2] + t[3])) + ((t[4] + t[5]) + (t[6] + t[7]));
      ts += __shfl_xor(ts, 32);
    }
    l_run = l_run * rr + ts;
#pragma unroll
    for (int i = 0; i < 16; i++) { o0[i] *= rr; o1[i] *= rr; }

    // ---- P -> PV B-fragments: cvt_pk pairs + cross-half swap + select ----
    // lane reg r holds k = (r&3)+8*(r>>2)+4*hi (+32 for s1). B-frag kc needs
    // k = kc*16 + hi*8 + j, j=0..7.
    const bool low = (hi == 0);
    PB pb[4];
    {
      unsigned c0 = cvtpk(s0[0], s0[1]),   c1 = cvtpk(s0[2], s0[3]);
      unsigned c2 = cvtpk(s0[4], s0[5]),   c3 = cvtpk(s0[6], s0[7]);
      unsigned c4 = cvtpk(s0[8], s0[9]),   c5 = cvtpk(s0[10], s0[11]);
      unsigned c6 = cvtpk(s0[12], s0[13]), c7 = cvtpk(s0[14], s0[15]);
      unsigned d0 = __shfl_xor((int)c0, 32), d1 = __shfl_xor((int)c1, 32);
      unsigned d2 = __shfl_xor((int)c2, 32), d3 = __shfl_xor((int)c3, 32);
      unsigned d4 = __shfl_xor((int)c4, 32), d5 = __shfl_xor((int)c5, 32);
      unsigned d6 = __shfl_xor((int)c6, 32), d7 = __shfl_xor((int)c7, 32);
      pb[0].u = (u32x4){low ? c0 : d2, low ? c1 : d3, low ? d0 : c2, low ? d1 : c3};
      pb[1].u = (u32x4){low ? c4 : d6, low ? c5 : d7, low ? d4 : c6, low ? d5 : c7};
    }
    {
      unsigned c0 = cvtpk(s1[0], s1[1]),   c1 = cvtpk(s1[2], s1[3]);
      unsigned c2 = cvtpk(s1[4], s1[5]),   c3 = cvtpk(s1[6], s1[7]);
      unsigned c4 = cvtpk(s1[8], s1[9]),   c5 = cvtpk(s1[10], s1[11]);
      unsigned c6 = cvtpk(s1[12], s1[13]), c7 = cvtpk(s1[14], s1[15]);
      unsigned d0 = __shfl_xor((int)c0, 32), d1 = __shfl_xor((int)c1, 32);
      unsigned d2 = __shfl_xor((int)c2, 32), d3 = __shfl_xor((int)c3, 32);
      unsigned d4 = __shfl_xor((int)c4, 32), d5 = __shfl_xor((int)c5, 32);
      unsigned d6 = __shfl_xor((int)c6, 32), d7 = __shfl_xor((int)c7, 32);
      pb[2].u = (u32x4){low ? c0 : d2, low ? c1 : d3, low ? d0 : c2, low ? d1 : c3};
      pb[3].u = (u32x4){low ? c4 : d6, low ? c5 : d7, low ? d4 : c6, low ? d5 : c7};
    }

    // ---- O^T += Vt · P : D[dh][q], col=lane&31=q (rescale stays lane-local)
#pragma unroll
    for (int kc = 0; kc < 4; kc++) {
      o0 = mfma32(vf[0][kc], pb[kc].b, o0);
      o1 = mfma32(vf[1][kc], pb[kc].b, o1);
    }
  }

  // ---- epilogue: ctx[q][h*64 + dh] = O^T[dh][q] / l ----
  const float inv = 1.0f / l_run;
  short* cp = ctx + (size_t)(b * T_SEQ + q) * 1024 + h * 64;
#pragma unroll
  for (int g = 0; g < 4; g++) {
    s16x4 w0, w1;
#pragma unroll
    for (int j = 0; j < 4; j++) {
      w0[j] = f2bf(o0[g * 4 + j] * inv);   // dh = g*8 + 4*hi + j
      w1[j] = f2bf(o1[g * 4 + j] * inv);   // dh = 32 + g*8 + 4*hi + j
    }
    *(s16x4*)(cp + g * 8 + 4 * hi) = w0;
    *(s16x4*)(cp + 32 + g * 8 + 4 * hi) = w1;
  }
}

// ---------------------------------------------------------------------------
extern "C" void kernel_launch(void* const* d_in, const int* in_sizes, int n_in,
                              void* d_out, int out_size, void* d_ws, size_t ws_size,
                              hipStream_t stream)
{
  (void)in_sizes; (void)n_in; (void)out_size; (void)ws_size;
  const float* x  = (const float*)d_in[0];
  // d_in[1] = causal mask (triu, k=1) — structure is known, not read
  const float* WQ = (const float*)d_in[2];
  const float* bQ = (const float*)d_in[3];
  const float* WK = (const float*)d_in[4];
  const float* bK = (const float*)d_in[5];
  const float* WV = (const float*)d_in[6];
  const float* bV = (const float*)d_in[7];
  const float* WO = (const float*)d_in[8];
  const float* bO = (const float*)d_in[9];
  float* out = (float*)d_out;

  const size_t MB = 1024ull * 1024ull;
  char* w = (char*)d_ws;
  short* xb = (short*)(w);             // 16MB; reused as ctx after QKV GEMMs
  short* Wt = (short*)(w + 16 * MB);   // 8MB: WQt,WKt,WVt,WOt bf16
  short* Qb = (short*)(w + 24 * MB);   // 16MB
  short* Kb = (short*)(w + 40 * MB);   // 16MB
  short* Vb = (short*)(w + 56 * MB);   // 16MB
  short* Vt = (short*)(w + 72 * MB);   // 16MB
  short* ctx = xb;

  transpose_w_kernel<<<dim3(32, 32, 4), 256, 0, stream>>>(WQ, WK, WV, WO, Wt);
  cvt_x_kernel<<<dim3(MTOK * D_MODEL / 8 / 256), 256, 0, stream>>>(x, xb);

  const float qscale = 0.125f * 1.4426950408889634f;  // fold 1/sqrt(64) * log2(e)
  gemm_bt<0><<<dim3(64, 8), 256, 0, stream>>>(xb, Wt + 0 * D_MODEL * D_MODEL, bQ, Qb, qscale);
  gemm_bt<0><<<dim3(64, 8), 256, 0, stream>>>(xb, Wt + 1 * D_MODEL * D_MODEL, bK, Kb, 1.0f);
  gemm_bt<0><<<dim3(64, 8), 256, 0, stream>>>(xb, Wt + 2 * D_MODEL * D_MODEL, bV, Vb, 1.0f);

  transpose_v_kernel<<<dim3(32, 64), 256, 0, stream>>>(Vb, Vt);
  attn_fwd<<<dim3(64, 64), 64, 0, stream>>>(Qb, Kb, Vt, ctx);

  gemm_bt<1><<<dim3(64, 8), 256, 0, stream>>>(ctx, Wt + 3 * D_MODEL * D_MODEL, bO, out, 1.0f);
}

// Round 5
// 254.807 us; speedup vs baseline: 2.2671x; 1.3091x over previous
//
#include <hip/hip_runtime.h>
#include <hip/hip_bf16.h>
#include <stdint.h>

#define T_SEQ   2048
#define D_MODEL 1024
#define NHEAD   16
#define DHEAD   64
#define BATCH   4
#define MTOK    (BATCH * T_SEQ)   // 8192

typedef __attribute__((ext_vector_type(4))) float f32x4;
typedef __attribute__((ext_vector_type(16))) float f32x16;
typedef __attribute__((ext_vector_type(8))) short bf16x8;
typedef __attribute__((ext_vector_type(4))) short s16x4;
typedef __attribute__((ext_vector_type(4))) unsigned u32x4;

__device__ __forceinline__ f32x4 mfma16(bf16x8 a, bf16x8 b, f32x4 c) {
  return __builtin_amdgcn_mfma_f32_16x16x32_bf16(a, b, c, 0, 0, 0);
}
__device__ __forceinline__ f32x16 mfma32(bf16x8 a, bf16x8 b, f32x16 c) {
  return __builtin_amdgcn_mfma_f32_32x32x16_bf16(a, b, c, 0, 0, 0);
}

__device__ __forceinline__ short f2bf(float f) {
  __hip_bfloat16 h = __float2bfloat16(f);
  return *reinterpret_cast<short*>(&h);
}

// v_cvt_pk_bf16_f32: dst = {lo16: bf16(a), hi16: bf16(b)} (no builtin on gfx950)
__device__ __forceinline__ unsigned cvtpk(float a, float b) {
  unsigned r;
  asm("v_cvt_pk_bf16_f32 %0, %1, %2" : "=v"(r) : "v"(a), "v"(b));
  return r;
}

union PB { u32x4 u; bf16x8 b; };

#define GLD_LDS16(gp, lp)                                                      \
  __builtin_amdgcn_global_load_lds(                                            \
      (const __attribute__((address_space(1))) void*)(gp),                     \
      (__attribute__((address_space(3))) void*)(lp), 16, 0, 0)

// ---------------------------------------------------------------------------
// Weight transpose + fp32->bf16 convert: Wt[n][k] = W[k][n], 4 weights
// ---------------------------------------------------------------------------
__global__ __launch_bounds__(256) void transpose_w_kernel(
    const float* __restrict__ W0, const float* __restrict__ W1,
    const float* __restrict__ W2, const float* __restrict__ W3,
    short* __restrict__ out)
{
  const int z = blockIdx.z;
  const float* W = (z == 0) ? W0 : (z == 1) ? W1 : (z == 2) ? W2 : W3;
  short* o = out + (size_t)z * D_MODEL * D_MODEL;
  __shared__ float tile[32][33];
  const int n0 = blockIdx.x * 32, k0 = blockIdx.y * 32;
  const int c = threadIdx.x & 31, r = threadIdx.x >> 5;
#pragma unroll
  for (int i = 0; i < 4; i++)
    tile[r + i * 8][c] = W[(size_t)(k0 + r + i * 8) * D_MODEL + n0 + c];
  __syncthreads();
#pragma unroll
  for (int i = 0; i < 4; i++)
    o[(size_t)(n0 + r + i * 8) * D_MODEL + k0 + c] = f2bf(tile[c][r + i * 8]);
}

// ---------------------------------------------------------------------------
// x fp32 -> bf16 (8 elements / thread)
// ---------------------------------------------------------------------------
__global__ __launch_bounds__(256) void cvt_x_kernel(
    const float* __restrict__ x, short* __restrict__ xb)
{
  const size_t i = (size_t)blockIdx.x * 256 + threadIdx.x;
  const float4 a = ((const float4*)x)[i * 2];
  const float4 b = ((const float4*)x)[i * 2 + 1];
  bf16x8 o;
  o[0] = f2bf(a.x); o[1] = f2bf(a.y); o[2] = f2bf(a.z); o[3] = f2bf(a.w);
  o[4] = f2bf(b.x); o[5] = f2bf(b.y); o[6] = f2bf(b.z); o[7] = f2bf(b.w);
  ((bf16x8*)xb)[i] = o;
}

// ---------------------------------------------------------------------------
// GEMM: C[M][1024] = A[M][1024](bf16) * Bt[1024][1024]^T(bf16, N-major) + bias
// 128x128 tile, BK=32, 4 waves (2x2), each wave 64x64 via 4x4 16x16x32 MFMA.
// MODE 0: bf16 out (scale applied after bias). MODE 1: fp32 out.
// ---------------------------------------------------------------------------
template <int MODE>
__global__ __launch_bounds__(256) void gemm_bt(
    const short* __restrict__ A, const short* __restrict__ Bt,
    const float* __restrict__ bias, void* __restrict__ Cp, float scale)
{
  __shared__ __align__(16) short As[128 * 32];
  __shared__ __align__(16) short Bs[128 * 32];
  const int tid = threadIdx.x, lane = tid & 63, wid = tid >> 6;
  const int wr = wid >> 1, wc = wid & 1;
  const int lg = lane >> 4, ln = lane & 15;
  const int m0 = blockIdx.x * 128, n0 = blockIdx.y * 128;
  const int lrow = lane >> 2, lchunk = lane & 3;

  f32x4 acc[4][4];
#pragma unroll
  for (int i = 0; i < 4; i++)
#pragma unroll
    for (int j = 0; j < 4; j++) acc[i][j] = {0.f, 0.f, 0.f, 0.f};

  for (int k0 = 0; k0 < 1024; k0 += 32) {
#pragma unroll
    for (int s = 0; s < 2; ++s) {
      const int rbase = (wid * 2 + s) * 16;
      const short* gpa = A + (size_t)(m0 + rbase + lrow) * 1024 + k0 + lchunk * 8;
      GLD_LDS16(gpa, As + rbase * 32);
      const short* gpb = Bt + (size_t)(n0 + rbase + lrow) * 1024 + k0 + lchunk * 8;
      GLD_LDS16(gpb, Bs + rbase * 32);
    }
    __syncthreads();
    bf16x8 a[4], b[4];
#pragma unroll
    for (int mi = 0; mi < 4; mi++)
      a[mi] = *(const bf16x8*)(As + (wr * 64 + mi * 16 + ln) * 32 + lg * 8);
#pragma unroll
    for (int ni = 0; ni < 4; ni++)
      b[ni] = *(const bf16x8*)(Bs + (wc * 64 + ni * 16 + ln) * 32 + lg * 8);
#pragma unroll
    for (int mi = 0; mi < 4; mi++)
#pragma unroll
      for (int ni = 0; ni < 4; ni++)
        acc[mi][ni] = mfma16(a[mi], b[ni], acc[mi][ni]);
    __syncthreads();
  }

#pragma unroll
  for (int mi = 0; mi < 4; mi++)
#pragma unroll
    for (int ni = 0; ni < 4; ni++)
#pragma unroll
      for (int r = 0; r < 4; r++) {
        const int row = m0 + wr * 64 + mi * 16 + lg * 4 + r;
        const int col = n0 + wc * 64 + ni * 16 + ln;
        const float v = (acc[mi][ni][r] + bias[col]) * scale;
        if (MODE == 0)
          ((short*)Cp)[(size_t)row * 1024 + col] = f2bf(v);
        else
          ((float*)Cp)[(size_t)row * 1024 + col] = v;
      }
}

// ---------------------------------------------------------------------------
// V [8192][1024] token-major -> Vt[b][h][dh][t]  (64x64 tiles via LDS)
// ---------------------------------------------------------------------------
__global__ __launch_bounds__(256) void transpose_v_kernel(
    const short* __restrict__ V, short* __restrict__ Vt)
{
  const int bh = blockIdx.y, t0 = blockIdx.x * 64;
  const int b = bh >> 4, h = bh & 15;
  __shared__ __align__(16) short tile[64][72];
  const int tl = threadIdx.x >> 3, c = threadIdx.x & 7;
#pragma unroll
  for (int half = 0; half < 2; half++) {
    const int t = tl + half * 32;
    bf16x8 v = *(const bf16x8*)(V + (size_t)(b * T_SEQ + t0 + t) * 1024 + h * 64 + c * 8);
    *(bf16x8*)&tile[t][c * 8] = v;
  }
  __syncthreads();
#pragma unroll
  for (int half = 0; half < 2; half++) {
    const int dh = tl + half * 32;
    bf16x8 v;
#pragma unroll
    for (int j = 0; j < 8; j++) v[j] = tile[c * 8 + j][dh];
    *(bf16x8*)(Vt + ((size_t)bh * 64 + dh) * T_SEQ + t0 + c * 8) = v;
  }
}

// ---------------------------------------------------------------------------
// Causal flash attention v4: swapped QK^T + in-register softmax (v3) plus
// (a) uniform work: each wave does q-tile pair (p, 63-p) => all 2048 waves
//     do 33-34 KV tiles; 4 waves/block, 2 blocks/CU flat residency;
// (b) register-pipelined K double-buffer (issue next-K under softmax/PV) and
//     early V issue (consumed at PV) => counted-vmcnt overlap, T14-style;
// (c) s_setprio(1) around MFMA clusters (independent-wave regime, m191).
// ---------------------------------------------------------------------------
#define ATTN_TILE(KC0, KC1, KN0, KN1, ITV, HASNEXT)                            \
  {                                                                            \
    const int kv0 = (ITV) * 64;                                                \
    bf16x8 vf0[4], vf1[4];                                                     \
    {                                                                          \
      const short* vp = Vt + (size_t)(bh * 64 + lq) * T_SEQ + kv0 + hi * 8;    \
      _Pragma("unroll")                                                        \
      for (int kc = 0; kc < 4; kc++) {                                         \
        vf0[kc] = *(const bf16x8*)(vp + kc * 16);                              \
        vf1[kc] = *(const bf16x8*)(vp + 32 * T_SEQ + kc * 16);                 \
      }                                                                        \
    }                                                                          \
    f32x16 s0, s1;                                                             \
    _Pragma("unroll")                                                          \
    for (int i = 0; i < 16; i++) { s0[i] = 0.f; s1[i] = 0.f; }                 \
    __builtin_amdgcn_s_setprio(1);                                             \
    _Pragma("unroll")                                                          \
    for (int c = 0; c < 4; c++) s0 = mfma32(KC0[c], qf[c], s0);                \
    _Pragma("unroll")                                                          \
    for (int c = 0; c < 4; c++) s1 = mfma32(KC1[c], qf[c], s1);                \
    __builtin_amdgcn_s_setprio(0);                                             \
    if (HASNEXT) {                                                             \
      const short* kp = K + (size_t)(b * T_SEQ + kv0 + 64 + lq) * 1024 +       \
                        h * 64 + hi * 8;                                       \
      _Pragma("unroll")                                                        \
      for (int c = 0; c < 4; c++) {                                            \
        KN0[c] = *(const bf16x8*)(kp + c * 16);                                \
        KN1[c] = *(const bf16x8*)(kp + 32 * 1024 + c * 16);                    \
      }                                                                        \
    }                                                                          \
    if (kv0 + 63 > qw) {                                                       \
      const int qrel = q - kv0 - 4 * hi;                                       \
      _Pragma("unroll")                                                        \
      for (int r = 0; r < 16; r++) {                                           \
        const int cst = (r & 3) + 8 * (r >> 2);                                \
        if (cst > qrel) s0[r] = -3.0e38f;                                      \
        if (cst + 32 > qrel) s1[r] = -3.0e38f;                                 \
      }                                                                        \
    }                                                                          \
    float mx;                                                                  \
    {                                                                          \
      float t[8];                                                              \
      _Pragma("unroll")                                                        \
      for (int i = 0; i < 8; i++)                                              \
        t[i] = fmaxf(fmaxf(s0[i], s0[i + 8]), fmaxf(s1[i], s1[i + 8]));        \
      const float a0 = fmaxf(fmaxf(t[0], t[1]), fmaxf(t[2], t[3]));            \
      const float a1 = fmaxf(fmaxf(t[4], t[5]), fmaxf(t[6], t[7]));            \
      mx = fmaxf(a0, a1);                                                      \
      mx = fmaxf(mx, __shfl_xor(mx, 32));                                      \
    }                                                                          \
    const float mn = fmaxf(m_run, mx);                                         \
    const float rr = exp2f(m_run - mn);                                        \
    m_run = mn;                                                                \
    _Pragma("unroll")                                                          \
    for (int i = 0; i < 16; i++) s0[i] = exp2f(s0[i] - mn);                    \
    _Pragma("unroll")                                                          \
    for (int i = 0; i < 16; i++) s1[i] = exp2f(s1[i] - mn);                    \
    float ts;                                                                  \
    {                                                                          \
      float t[8];                                                              \
      _Pragma("unroll")                                                        \
      for (int i = 0; i < 8; i++)                                              \
        t[i] = (s0[i] + s0[i + 8]) + (s1[i] + s1[i + 8]);                      \
      ts = ((t[0] + t[1]) + (t[2] + t[3])) + ((t[4] + t[5]) + (t[6] + t[7]));  \
      ts += __shfl_xor(ts, 32);                                                \
    }                                                                          \
    l_run = l_run * rr + ts;                                                   \
    _Pragma("unroll")                                                          \
    for (int i = 0; i < 16; i++) { o0[i] *= rr; o1[i] *= rr; }                 \
    const bool low = (hi == 0);                                                \
    PB pb[4];                                                                  \
    {                                                                          \
      unsigned c0 = cvtpk(s0[0], s0[1]),   c1 = cvtpk(s0[2], s0[3]);           \
      unsigned c2 = cvtpk(s0[4], s0[5]),   c3 = cvtpk(s0[6], s0[7]);           \
      unsigned c4 = cvtpk(s0[8], s0[9]),   c5 = cvtpk(s0[10], s0[11]);         \
      unsigned c6 = cvtpk(s0[12], s0[13]), c7 = cvtpk(s0[14], s0[15]);         \
      unsigned d0 = __shfl_xor((int)c0, 32), d1 = __shfl_xor((int)c1, 32);     \
      unsigned d2 = __shfl_xor((int)c2, 32), d3 = __shfl_xor((int)c3, 32);     \
      unsigned d4 = __shfl_xor((int)c4, 32), d5 = __shfl_xor((int)c5, 32);     \
      unsigned d6 = __shfl_xor((int)c6, 32), d7 = __shfl_xor((int)c7, 32);     \
      pb[0].u = (u32x4){low ? c0 : d2, low ? c1 : d3, low ? d0 : c2, low ? d1 : c3}; \
      pb[1].u = (u32x4){low ? c4 : d6, low ? c5 : d7, low ? d4 : c6, low ? d5 : c7}; \
    }                                                                          \
    {                                                                          \
      unsigned c0 = cvtpk(s1[0], s1[1]),   c1 = cvtpk(s1[2], s1[3]);           \
      unsigned c2 = cvtpk(s1[4], s1[5]),   c3 = cvtpk(s1[6], s1[7]);           \
      unsigned c4 = cvtpk(s1[8], s1[9]),   c5 = cvtpk(s1[10], s1[11]);         \
      unsigned c6 = cvtpk(s1[12], s1[13]), c7 = cvtpk(s1[14], s1[15]);         \
      unsigned d0 = __shfl_xor((int)c0, 32), d1 = __shfl_xor((int)c1, 32);     \
      unsigned d2 = __shfl_xor((int)c2, 32), d3 = __shfl_xor((int)c3, 32);     \
      unsigned d4 = __shfl_xor((int)c4, 32), d5 = __shfl_xor((int)c5, 32);     \
      unsigned d6 = __shfl_xor((int)c6, 32), d7 = __shfl_xor((int)c7, 32);     \
      pb[2].u = (u32x4){low ? c0 : d2, low ? c1 : d3, low ? d0 : c2, low ? d1 : c3}; \
      pb[3].u = (u32x4){low ? c4 : d6, low ? c5 : d7, low ? d4 : c6, low ? d5 : c7}; \
    }                                                                          \
    __builtin_amdgcn_s_setprio(1);                                             \
    _Pragma("unroll")                                                          \
    for (int kc = 0; kc < 4; kc++) {                                           \
      o0 = mfma32(vf0[kc], pb[kc].b, o0);                                      \
      o1 = mfma32(vf1[kc], pb[kc].b, o1);                                      \
    }                                                                          \
    __builtin_amdgcn_s_setprio(0);                                             \
  }

__global__ __launch_bounds__(256, 2) void attn_fwd(
    const short* __restrict__ Q, const short* __restrict__ K,
    const short* __restrict__ Vt, short* __restrict__ ctx)
{
  const int tid = threadIdx.x, lane = tid & 63, wid = tid >> 6;
  const int hi = lane >> 5, lq = lane & 31;
  const int p = blockIdx.x * 4 + wid;           // pair index 0..31
  const int bh = blockIdx.y, b = bh >> 4, h = bh & 15;

#pragma unroll 1
  for (int pass = 0; pass < 2; ++pass) {
    const int qt = (pass == 0) ? p : 63 - p;
    const int qw = qt * 32;
    const int q = qw + lq;

    // Q B-fragments: Q[q=lane&31][dh = c*16 + hi*8 + j]
    bf16x8 qf[4];
    {
      const short* qp = Q + (size_t)(b * T_SEQ + q) * 1024 + h * 64 + hi * 8;
#pragma unroll
      for (int c = 0; c < 4; c++) qf[c] = *(const bf16x8*)(qp + c * 16);
    }

    f32x16 o0, o1;
#pragma unroll
    for (int i = 0; i < 16; i++) { o0[i] = 0.f; o1[i] = 0.f; }
    float m_run = -3.0e38f, l_run = 0.f;

    const int nt = (qw + 95) >> 6;              // kv tiles of 64
    bf16x8 kfA0[4], kfA1[4], kfB0[4], kfB1[4];
    {
      const short* kp = K + (size_t)(b * T_SEQ + lq) * 1024 + h * 64 + hi * 8;
#pragma unroll
      for (int c = 0; c < 4; c++) {
        kfA0[c] = *(const bf16x8*)(kp + c * 16);
        kfA1[c] = *(const bf16x8*)(kp + 32 * 1024 + c * 16);
      }
    }
    int it = 0;
#pragma unroll 1
    for (; it + 2 <= nt; it += 2) {
      ATTN_TILE(kfA0, kfA1, kfB0, kfB1, it, true)
      ATTN_TILE(kfB0, kfB1, kfA0, kfA1, it + 1, (it + 2 < nt))
    }
    if (it < nt) ATTN_TILE(kfA0, kfA1, kfB0, kfB1, it, false)

    // epilogue: ctx[q][h*64 + dh] = O^T[dh][q] / l
    const float inv = 1.0f / l_run;
    short* cp = ctx + (size_t)(b * T_SEQ + q) * 1024 + h * 64;
#pragma unroll
    for (int g = 0; g < 4; g++) {
      s16x4 w0, w1;
#pragma unroll
      for (int j = 0; j < 4; j++) {
        w0[j] = f2bf(o0[g * 4 + j] * inv);   // dh = g*8 + 4*hi + j
        w1[j] = f2bf(o1[g * 4 + j] * inv);   // dh = 32 + g*8 + 4*hi + j
      }
      *(s16x4*)(cp + g * 8 + 4 * hi) = w0;
      *(s16x4*)(cp + 32 + g * 8 + 4 * hi) = w1;
    }
  }
}

// ---------------------------------------------------------------------------
extern "C" void kernel_launch(void* const* d_in, const int* in_sizes, int n_in,
                              void* d_out, int out_size, void* d_ws, size_t ws_size,
                              hipStream_t stream)
{
  (void)in_sizes; (void)n_in; (void)out_size; (void)ws_size;
  const float* x  = (const float*)d_in[0];
  // d_in[1] = causal mask (triu, k=1) — structure is known, not read
  const float* WQ = (const float*)d_in[2];
  const float* bQ = (const float*)d_in[3];
  const float* WK = (const float*)d_in[4];
  const float* bK = (const float*)d_in[5];
  const float* WV = (const float*)d_in[6];
  const float* bV = (const float*)d_in[7];
  const float* WO = (const float*)d_in[8];
  const float* bO = (const float*)d_in[9];
  float* out = (float*)d_out;

  const size_t MB = 1024ull * 1024ull;
  char* w = (char*)d_ws;
  short* xb = (short*)(w);             // 16MB; reused as ctx after QKV GEMMs
  short* Wt = (short*)(w + 16 * MB);   // 8MB: WQt,WKt,WVt,WOt bf16
  short* Qb = (short*)(w + 24 * MB);   // 16MB
  short* Kb = (short*)(w + 40 * MB);   // 16MB
  short* Vb = (short*)(w + 56 * MB);   // 16MB
  short* Vt = (short*)(w + 72 * MB);   // 16MB
  short* ctx = xb;

  transpose_w_kernel<<<dim3(32, 32, 4), 256, 0, stream>>>(WQ, WK, WV, WO, Wt);
  cvt_x_kernel<<<dim3(MTOK * D_MODEL / 8 / 256), 256, 0, stream>>>(x, xb);

  const float qscale = 0.125f * 1.4426950408889634f;  // fold 1/sqrt(64) * log2(e)
  gemm_bt<0><<<dim3(64, 8), 256, 0, stream>>>(xb, Wt + 0 * D_MODEL * D_MODEL, bQ, Qb, qscale);
  gemm_bt<0><<<dim3(64, 8), 256, 0, stream>>>(xb, Wt + 1 * D_MODEL * D_MODEL, bK, Kb, 1.0f);
  gemm_bt<0><<<dim3(64, 8), 256, 0, stream>>>(xb, Wt + 2 * D_MODEL * D_MODEL, bV, Vb, 1.0f);

  transpose_v_kernel<<<dim3(32, 64), 256, 0, stream>>>(Vb, Vt);
  attn_fwd<<<dim3(8, 64), 256, 0, stream>>>(Qb, Kb, Vt, ctx);

  gemm_bt<1><<<dim3(64, 8), 256, 0, stream>>>(ctx, Wt + 3 * D_MODEL * D_MODEL, bO, out, 1.0f);
}

// Round 6
// 236.012 us; speedup vs baseline: 2.4476x; 1.0796x over previous
//
#include <hip/hip_runtime.h>
#include <hip/hip_bf16.h>
#include <stdint.h>

#define T_SEQ   2048
#define D_MODEL 1024
#define NHEAD   16
#define DHEAD   64
#define BATCH   4
#define MTOK    (BATCH * T_SEQ)   // 8192

typedef __attribute__((ext_vector_type(4))) float f32x4;
typedef __attribute__((ext_vector_type(16))) float f32x16;
typedef __attribute__((ext_vector_type(8))) short bf16x8;
typedef __attribute__((ext_vector_type(4))) short s16x4;
typedef __attribute__((ext_vector_type(4))) unsigned u32x4;

__device__ __forceinline__ f32x4 mfma16(bf16x8 a, bf16x8 b, f32x4 c) {
  return __builtin_amdgcn_mfma_f32_16x16x32_bf16(a, b, c, 0, 0, 0);
}
__device__ __forceinline__ f32x16 mfma32(bf16x8 a, bf16x8 b, f32x16 c) {
  return __builtin_amdgcn_mfma_f32_32x32x16_bf16(a, b, c, 0, 0, 0);
}

__device__ __forceinline__ short f2bf(float f) {
  __hip_bfloat16 h = __float2bfloat16(f);
  return *reinterpret_cast<short*>(&h);
}

// v_cvt_pk_bf16_f32: dst = {lo16: bf16(a), hi16: bf16(b)} (no builtin on gfx950)
__device__ __forceinline__ unsigned cvtpk(float a, float b) {
  unsigned r;
  asm("v_cvt_pk_bf16_f32 %0, %1, %2" : "=v"(r) : "v"(a), "v"(b));
  return r;
}

union PB { u32x4 u; bf16x8 b; };

#define GLD_LDS16(gp, lp)                                                      \
  __builtin_amdgcn_global_load_lds(                                            \
      (const __attribute__((address_space(1))) void*)(gp),                     \
      (__attribute__((address_space(3))) void*)(lp), 16, 0, 0)

// ---------------------------------------------------------------------------
// Weight transpose + fp32->bf16 convert: Wt[n][k] = W[k][n], 4 weights
// ---------------------------------------------------------------------------
__global__ __launch_bounds__(256) void transpose_w_kernel(
    const float* __restrict__ W0, const float* __restrict__ W1,
    const float* __restrict__ W2, const float* __restrict__ W3,
    short* __restrict__ out)
{
  const int z = blockIdx.z;
  const float* W = (z == 0) ? W0 : (z == 1) ? W1 : (z == 2) ? W2 : W3;
  short* o = out + (size_t)z * D_MODEL * D_MODEL;
  __shared__ float tile[32][33];
  const int n0 = blockIdx.x * 32, k0 = blockIdx.y * 32;
  const int c = threadIdx.x & 31, r = threadIdx.x >> 5;
#pragma unroll
  for (int i = 0; i < 4; i++)
    tile[r + i * 8][c] = W[(size_t)(k0 + r + i * 8) * D_MODEL + n0 + c];
  __syncthreads();
#pragma unroll
  for (int i = 0; i < 4; i++)
    o[(size_t)(n0 + r + i * 8) * D_MODEL + k0 + c] = f2bf(tile[c][r + i * 8]);
}

// ---------------------------------------------------------------------------
// x fp32 -> bf16 (8 elements / thread)
// ---------------------------------------------------------------------------
__global__ __launch_bounds__(256) void cvt_x_kernel(
    const float* __restrict__ x, short* __restrict__ xb)
{
  const size_t i = (size_t)blockIdx.x * 256 + threadIdx.x;
  const float4 a = ((const float4*)x)[i * 2];
  const float4 b = ((const float4*)x)[i * 2 + 1];
  bf16x8 o;
  o[0] = f2bf(a.x); o[1] = f2bf(a.y); o[2] = f2bf(a.z); o[3] = f2bf(a.w);
  o[4] = f2bf(b.x); o[5] = f2bf(b.y); o[6] = f2bf(b.z); o[7] = f2bf(b.w);
  ((bf16x8*)xb)[i] = o;
}

// ---------------------------------------------------------------------------
// GEMM: C[M][1024] = A[M][1024](bf16) * Bt[1024][1024]^T(bf16, N-major) + bias
// 128x128 tile, BK=32, 4 waves (2x2), each wave 64x64 via 4x4 16x16x32 MFMA.
// MODE 0: bf16 out (scale applied after bias). MODE 1: fp32 out.
// ---------------------------------------------------------------------------
template <int MODE>
__global__ __launch_bounds__(256) void gemm_bt(
    const short* __restrict__ A, const short* __restrict__ Bt,
    const float* __restrict__ bias, void* __restrict__ Cp, float scale)
{
  __shared__ __align__(16) short As[128 * 32];
  __shared__ __align__(16) short Bs[128 * 32];
  const int tid = threadIdx.x, lane = tid & 63, wid = tid >> 6;
  const int wr = wid >> 1, wc = wid & 1;
  const int lg = lane >> 4, ln = lane & 15;
  const int m0 = blockIdx.x * 128, n0 = blockIdx.y * 128;
  const int lrow = lane >> 2, lchunk = lane & 3;

  f32x4 acc[4][4];
#pragma unroll
  for (int i = 0; i < 4; i++)
#pragma unroll
    for (int j = 0; j < 4; j++) acc[i][j] = {0.f, 0.f, 0.f, 0.f};

  for (int k0 = 0; k0 < 1024; k0 += 32) {
#pragma unroll
    for (int s = 0; s < 2; ++s) {
      const int rbase = (wid * 2 + s) * 16;
      const short* gpa = A + (size_t)(m0 + rbase + lrow) * 1024 + k0 + lchunk * 8;
      GLD_LDS16(gpa, As + rbase * 32);
      const short* gpb = Bt + (size_t)(n0 + rbase + lrow) * 1024 + k0 + lchunk * 8;
      GLD_LDS16(gpb, Bs + rbase * 32);
    }
    __syncthreads();
    bf16x8 a[4], b[4];
#pragma unroll
    for (int mi = 0; mi < 4; mi++)
      a[mi] = *(const bf16x8*)(As + (wr * 64 + mi * 16 + ln) * 32 + lg * 8);
#pragma unroll
    for (int ni = 0; ni < 4; ni++)
      b[ni] = *(const bf16x8*)(Bs + (wc * 64 + ni * 16 + ln) * 32 + lg * 8);
#pragma unroll
    for (int mi = 0; mi < 4; mi++)
#pragma unroll
      for (int ni = 0; ni < 4; ni++)
        acc[mi][ni] = mfma16(a[mi], b[ni], acc[mi][ni]);
    __syncthreads();
  }

#pragma unroll
  for (int mi = 0; mi < 4; mi++)
#pragma unroll
    for (int ni = 0; ni < 4; ni++)
#pragma unroll
      for (int r = 0; r < 4; r++) {
        const int row = m0 + wr * 64 + mi * 16 + lg * 4 + r;
        const int col = n0 + wc * 64 + ni * 16 + ln;
        const float v = (acc[mi][ni][r] + bias[col]) * scale;
        if (MODE == 0)
          ((short*)Cp)[(size_t)row * 1024 + col] = f2bf(v);
        else
          ((float*)Cp)[(size_t)row * 1024 + col] = v;
      }
}

// ---------------------------------------------------------------------------
// V [8192][1024] token-major -> Vt[b][h][dh][t]  (64x64 tiles via LDS)
// ---------------------------------------------------------------------------
__global__ __launch_bounds__(256) void transpose_v_kernel(
    const short* __restrict__ V, short* __restrict__ Vt)
{
  const int bh = blockIdx.y, t0 = blockIdx.x * 64;
  const int b = bh >> 4, h = bh & 15;
  __shared__ __align__(16) short tile[64][72];
  const int tl = threadIdx.x >> 3, c = threadIdx.x & 7;
#pragma unroll
  for (int half = 0; half < 2; half++) {
    const int t = tl + half * 32;
    bf16x8 v = *(const bf16x8*)(V + (size_t)(b * T_SEQ + t0 + t) * 1024 + h * 64 + c * 8);
    *(bf16x8*)&tile[t][c * 8] = v;
  }
  __syncthreads();
#pragma unroll
  for (int half = 0; half < 2; half++) {
    const int dh = tl + half * 32;
    bf16x8 v;
#pragma unroll
    for (int j = 0; j < 8; j++) v[j] = tile[c * 8 + j][dh];
    *(bf16x8*)(Vt + ((size_t)bh * 64 + dh) * T_SEQ + t0 + c * 8) = v;
  }
}

// ---------------------------------------------------------------------------
// Causal flash attention v5: dual-q chains per wave.
// Each wave owns the q-tile pair (p, 63-p) and sweeps KV ONCE: per 64-wide
// KV tile, shared K/V register fragments feed two independent
// {QK^T -> softmax -> PV} chains (B = long tile always; A = short tile while
// it < ntA). 2 chains/wave x 2 waves/SIMD = 4-way chain overlap; K/V traffic
// halves vs the 2-pass scheme. XCD swizzle: the 8 blocks of one bh map to one
// XCD's L2 (KV = 0.5 MB/bh). Swapped QK^T / in-register softmax as v3/v4.
// ---------------------------------------------------------------------------
__device__ __forceinline__ void tile_chain(
    const bf16x8* kf0, const bf16x8* kf1,
    const bf16x8* vf0, const bf16x8* vf1,
    const bf16x8* qf,
    f32x16& o0, f32x16& o1, float& m_run, float& l_run,
    const int kv0, const int qw, const int q, const int hi)
{
  f32x16 s0, s1;
#pragma unroll
  for (int i = 0; i < 16; i++) { s0[i] = 0.f; s1[i] = 0.f; }
  __builtin_amdgcn_s_setprio(1);
#pragma unroll
  for (int c = 0; c < 4; c++) s0 = mfma32(kf0[c], qf[c], s0);
#pragma unroll
  for (int c = 0; c < 4; c++) s1 = mfma32(kf1[c], qf[c], s1);
  __builtin_amdgcn_s_setprio(0);

  if (kv0 + 63 > qw) {
    const int qrel = q - kv0 - 4 * hi;
#pragma unroll
    for (int r = 0; r < 16; r++) {
      const int cst = (r & 3) + 8 * (r >> 2);
      if (cst > qrel) s0[r] = -3.0e38f;
      if (cst + 32 > qrel) s1[r] = -3.0e38f;
    }
  }

  float mx;
  {
    float t[8];
#pragma unroll
    for (int i = 0; i < 8; i++)
      t[i] = fmaxf(fmaxf(s0[i], s0[i + 8]), fmaxf(s1[i], s1[i + 8]));
    const float a0 = fmaxf(fmaxf(t[0], t[1]), fmaxf(t[2], t[3]));
    const float a1 = fmaxf(fmaxf(t[4], t[5]), fmaxf(t[6], t[7]));
    mx = fmaxf(a0, a1);
    mx = fmaxf(mx, __shfl_xor(mx, 32));
  }
  const float mn = fmaxf(m_run, mx);
  const float rr = exp2f(m_run - mn);
  m_run = mn;
#pragma unroll
  for (int i = 0; i < 16; i++) s0[i] = exp2f(s0[i] - mn);
#pragma unroll
  for (int i = 0; i < 16; i++) s1[i] = exp2f(s1[i] - mn);
  float ts;
  {
    float t[8];
#pragma unroll
    for (int i = 0; i < 8; i++) t[i] = (s0[i] + s0[i + 8]) + (s1[i] + s1[i + 8]);
    ts = ((t[0] + t[1]) + (t[2] + t[3])) + ((t[4] + t[5]) + (t[6] + t[7]));
    ts += __shfl_xor(ts, 32);
  }
  l_run = l_run * rr + ts;
#pragma unroll
  for (int i = 0; i < 16; i++) { o0[i] *= rr; o1[i] *= rr; }

  // P -> PV B-fragments: cvt_pk pairs + cross-half swap + select
  const bool low = (hi == 0);
  PB pb[4];
  {
    unsigned c0 = cvtpk(s0[0], s0[1]),   c1 = cvtpk(s0[2], s0[3]);
    unsigned c2 = cvtpk(s0[4], s0[5]),   c3 = cvtpk(s0[6], s0[7]);
    unsigned c4 = cvtpk(s0[8], s0[9]),   c5 = cvtpk(s0[10], s0[11]);
    unsigned c6 = cvtpk(s0[12], s0[13]), c7 = cvtpk(s0[14], s0[15]);
    unsigned d0 = __shfl_xor((int)c0, 32), d1 = __shfl_xor((int)c1, 32);
    unsigned d2 = __shfl_xor((int)c2, 32), d3 = __shfl_xor((int)c3, 32);
    unsigned d4 = __shfl_xor((int)c4, 32), d5 = __shfl_xor((int)c5, 32);
    unsigned d6 = __shfl_xor((int)c6, 32), d7 = __shfl_xor((int)c7, 32);
    pb[0].u = (u32x4){low ? c0 : d2, low ? c1 : d3, low ? d0 : c2, low ? d1 : c3};
    pb[1].u = (u32x4){low ? c4 : d6, low ? c5 : d7, low ? d4 : c6, low ? d5 : c7};
  }
  {
    unsigned c0 = cvtpk(s1[0], s1[1]),   c1 = cvtpk(s1[2], s1[3]);
    unsigned c2 = cvtpk(s1[4], s1[5]),   c3 = cvtpk(s1[6], s1[7]);
    unsigned c4 = cvtpk(s1[8], s1[9]),   c5 = cvtpk(s1[10], s1[11]);
    unsigned c6 = cvtpk(s1[12], s1[13]), c7 = cvtpk(s1[14], s1[15]);
    unsigned d0 = __shfl_xor((int)c0, 32), d1 = __shfl_xor((int)c1, 32);
    unsigned d2 = __shfl_xor((int)c2, 32), d3 = __shfl_xor((int)c3, 32);
    unsigned d4 = __shfl_xor((int)c4, 32), d5 = __shfl_xor((int)c5, 32);
    unsigned d6 = __shfl_xor((int)c6, 32), d7 = __shfl_xor((int)c7, 32);
    pb[2].u = (u32x4){low ? c0 : d2, low ? c1 : d3, low ? d0 : c2, low ? d1 : c3};
    pb[3].u = (u32x4){low ? c4 : d6, low ? c5 : d7, low ? d4 : c6, low ? d5 : c7};
  }

  __builtin_amdgcn_s_setprio(1);
#pragma unroll
  for (int kc = 0; kc < 4; kc++) {
    o0 = mfma32(vf0[kc], pb[kc].b, o0);
    o1 = mfma32(vf1[kc], pb[kc].b, o1);
  }
  __builtin_amdgcn_s_setprio(0);
}

__device__ __forceinline__ void attn_epilogue(
    short* cp, const f32x16& o0, const f32x16& o1, float l_run, int hi)
{
  const float inv = 1.0f / l_run;
#pragma unroll
  for (int g = 0; g < 4; g++) {
    s16x4 w0, w1;
#pragma unroll
    for (int j = 0; j < 4; j++) {
      w0[j] = f2bf(o0[g * 4 + j] * inv);   // dh = g*8 + 4*hi + j
      w1[j] = f2bf(o1[g * 4 + j] * inv);   // dh = 32 + g*8 + 4*hi + j
    }
    *(s16x4*)(cp + g * 8 + 4 * hi) = w0;
    *(s16x4*)(cp + 32 + g * 8 + 4 * hi) = w1;
  }
}

__global__ __launch_bounds__(256, 2) void attn_fwd(
    const short* __restrict__ Q, const short* __restrict__ K,
    const short* __restrict__ Vt, short* __restrict__ ctx)
{
  const int tid = threadIdx.x, lane = tid & 63, wid = tid >> 6;
  const int hi = lane >> 5, lq = lane & 31;
  // XCD swizzle: 512 blocks, id%8 = XCD (round-robin). All 8 blocks of one
  // bh land on one XCD: bh = (id&7)*8 + ((id>>3)&7); x-slot = id>>6.
  const int id = (int)blockIdx.x;
  const int bh = (id & 7) * 8 + ((id >> 3) & 7);
  const int p = (id >> 6) * 4 + wid;            // pair index 0..31
  const int b = bh >> 4, h = bh & 15;

  const int qtA = p, qtB = 63 - p;
  const int qwA = qtA * 32, qwB = qtB * 32;
  const int qA = qwA + lq, qB = qwB + lq;

  bf16x8 qfA[4], qfB[4];
  {
    const short* qpA = Q + (size_t)(b * T_SEQ + qA) * 1024 + h * 64 + hi * 8;
    const short* qpB = Q + (size_t)(b * T_SEQ + qB) * 1024 + h * 64 + hi * 8;
#pragma unroll
    for (int c = 0; c < 4; c++) {
      qfA[c] = *(const bf16x8*)(qpA + c * 16);
      qfB[c] = *(const bf16x8*)(qpB + c * 16);
    }
  }

  f32x16 oA0, oA1, oB0, oB1;
#pragma unroll
  for (int i = 0; i < 16; i++) { oA0[i] = 0.f; oA1[i] = 0.f; oB0[i] = 0.f; oB1[i] = 0.f; }
  float mA = -3.0e38f, lA = 0.f, mB = -3.0e38f, lB = 0.f;

  const int ntA = (qwA + 95) >> 6, ntB = (qwB + 95) >> 6;

  int it = 0;
#pragma unroll 1
  for (; it < ntA; ++it) {
    const int kv0 = it * 64;
    bf16x8 kf0[4], kf1[4], vf0[4], vf1[4];
    {
      const short* kp = K + (size_t)(b * T_SEQ + kv0 + lq) * 1024 + h * 64 + hi * 8;
      const short* vp = Vt + (size_t)(bh * 64 + lq) * T_SEQ + kv0 + hi * 8;
#pragma unroll
      for (int c = 0; c < 4; c++) {
        kf0[c] = *(const bf16x8*)(kp + c * 16);
        kf1[c] = *(const bf16x8*)(kp + 32 * 1024 + c * 16);
        vf0[c] = *(const bf16x8*)(vp + c * 16);
        vf1[c] = *(const bf16x8*)(vp + 32 * T_SEQ + c * 16);
      }
    }
    tile_chain(kf0, kf1, vf0, vf1, qfB, oB0, oB1, mB, lB, kv0, qwB, qB, hi);
    tile_chain(kf0, kf1, vf0, vf1, qfA, oA0, oA1, mA, lA, kv0, qwA, qA, hi);
  }
#pragma unroll 1
  for (; it < ntB; ++it) {
    const int kv0 = it * 64;
    bf16x8 kf0[4], kf1[4], vf0[4], vf1[4];
    {
      const short* kp = K + (size_t)(b * T_SEQ + kv0 + lq) * 1024 + h * 64 + hi * 8;
      const short* vp = Vt + (size_t)(bh * 64 + lq) * T_SEQ + kv0 + hi * 8;
#pragma unroll
      for (int c = 0; c < 4; c++) {
        kf0[c] = *(const bf16x8*)(kp + c * 16);
        kf1[c] = *(const bf16x8*)(kp + 32 * 1024 + c * 16);
        vf0[c] = *(const bf16x8*)(vp + c * 16);
        vf1[c] = *(const bf16x8*)(vp + 32 * T_SEQ + c * 16);
      }
    }
    tile_chain(kf0, kf1, vf0, vf1, qfB, oB0, oB1, mB, lB, kv0, qwB, qB, hi);
  }

  attn_epilogue(ctx + (size_t)(b * T_SEQ + qA) * 1024 + h * 64, oA0, oA1, lA, hi);
  attn_epilogue(ctx + (size_t)(b * T_SEQ + qB) * 1024 + h * 64, oB0, oB1, lB, hi);
}

// ---------------------------------------------------------------------------
extern "C" void kernel_launch(void* const* d_in, const int* in_sizes, int n_in,
                              void* d_out, int out_size, void* d_ws, size_t ws_size,
                              hipStream_t stream)
{
  (void)in_sizes; (void)n_in; (void)out_size; (void)ws_size;
  const float* x  = (const float*)d_in[0];
  // d_in[1] = causal mask (triu, k=1) — structure is known, not read
  const float* WQ = (const float*)d_in[2];
  const float* bQ = (const float*)d_in[3];
  const float* WK = (const float*)d_in[4];
  const float* bK = (const float*)d_in[5];
  const float* WV = (const float*)d_in[6];
  const float* bV = (const float*)d_in[7];
  const float* WO = (const float*)d_in[8];
  const float* bO = (const float*)d_in[9];
  float* out = (float*)d_out;

  const size_t MB = 1024ull * 1024ull;
  char* w = (char*)d_ws;
  short* xb = (short*)(w);             // 16MB; reused as ctx after QKV GEMMs
  short* Wt = (short*)(w + 16 * MB);   // 8MB: WQt,WKt,WVt,WOt bf16
  short* Qb = (short*)(w + 24 * MB);   // 16MB
  short* Kb = (short*)(w + 40 * MB);   // 16MB
  short* Vb = (short*)(w + 56 * MB);   // 16MB
  short* Vt = (short*)(w + 72 * MB);   // 16MB
  short* ctx = xb;

  transpose_w_kernel<<<dim3(32, 32, 4), 256, 0, stream>>>(WQ, WK, WV, WO, Wt);
  cvt_x_kernel<<<dim3(MTOK * D_MODEL / 8 / 256), 256, 0, stream>>>(x, xb);

  const float qscale = 0.125f * 1.4426950408889634f;  // fold 1/sqrt(64) * log2(e)
  gemm_bt<0><<<dim3(64, 8), 256, 0, stream>>>(xb, Wt + 0 * D_MODEL * D_MODEL, bQ, Qb, qscale);
  gemm_bt<0><<<dim3(64, 8), 256, 0, stream>>>(xb, Wt + 1 * D_MODEL * D_MODEL, bK, Kb, 1.0f);
  gemm_bt<0><<<dim3(64, 8), 256, 0, stream>>>(xb, Wt + 2 * D_MODEL * D_MODEL, bV, Vb, 1.0f);

  transpose_v_kernel<<<dim3(32, 64), 256, 0, stream>>>(Vb, Vt);
  attn_fwd<<<dim3(512), 256, 0, stream>>>(Qb, Kb, Vt, ctx);

  gemm_bt<1><<<dim3(64, 8), 256, 0, stream>>>(ctx, Wt + 3 * D_MODEL * D_MODEL, bO, out, 1.0f);
}